// Round 1
// baseline (162.458 us; speedup 1.0000x reference)
//
#include <hip/hip_runtime.h>
#include <math.h>

// Level geometry (fixed by reference: strides 4/8/16, H=W=160/80/40)
#define NL0 25600   // 160*160
#define NL1 6400    // 80*80
#define NL2 1600    // 40*40
#define NTOT 33600  // sum
#define MAXM 64

__device__ __forceinline__ float logsig(float x) {
    // numerically stable log(sigmoid(x))
    return fminf(x, 0.0f) - log1pf(expf(-fabsf(x)));
}

__global__ void fcos_zero(float* acc) {
    if (threadIdx.x < 4) acc[threadIdx.x] = 0.0f;
}

__global__ __launch_bounds__(256) void fcos_main(
    const float* __restrict__ cls0, const float* __restrict__ cls1,
    const float* __restrict__ cls2, const float* __restrict__ reg0,
    const float* __restrict__ reg1, const float* __restrict__ reg2,
    const float* __restrict__ boxes, int M, float* __restrict__ acc)
{
    const int b = blockIdx.y;
    const int i = blockIdx.x * 256 + threadIdx.x;

    __shared__ float sb[MAXM * 4];
    __shared__ float sarea[MAXM];
    // stage this image's boxes into LDS
    for (int t = threadIdx.x; t < 4 * M; t += 256)
        sb[t] = boxes[(size_t)b * 4 * M + t];
    __syncthreads();
    if (threadIdx.x < M) {
        int j = threadIdx.x;
        sarea[j] = (sb[4*j+2] - sb[4*j]) * (sb[4*j+3] - sb[4*j+1]);
    }
    __syncthreads();

    float clsl = 0.0f, regl = 0.0f, posf = 0.0f;

    if (i < NTOT) {
        int ii, W, hw;
        float s, low, high;
        const float* cbase;
        const float* rbase;
        if (i < NL0)            { ii = i;                W = 160; s = 4.0f;  low = -1.0f;  high = 64.0f;    hw = NL0; cbase = cls0; rbase = reg0; }
        else if (i < NL0 + NL1) { ii = i - NL0;          W = 80;  s = 8.0f;  low = 64.0f;  high = 128.0f;   hw = NL1; cbase = cls1; rbase = reg1; }
        else                    { ii = i - (NL0 + NL1);  W = 40;  s = 16.0f; low = 128.0f; high = 99999.0f; hw = NL2; cbase = cls2; rbase = reg2; }
        const int h = ii / W;
        const int w = ii - h * W;
        const float x = ((float)w + 0.5f) * s;
        const float y = ((float)h + 0.5f) * s;

        // argmin over boxes (first occurrence of min via strict <)
        float best = INFINITY;
        int idx = 0;
        #pragma unroll 8
        for (int j = 0; j < M; j++) {
            const float x0 = sb[4*j], y0 = sb[4*j+1], x1 = sb[4*j+2], y1 = sb[4*j+3];
            const float l = x - x0, t = y - y0, r = x1 - x, bo = y1 - y;
            const float mn = fminf(fminf(l, t), fminf(r, bo));
            const float mx = fmaxf(fmaxf(l, t), fmaxf(r, bo));
            const bool ok = (mn > 0.0f) & (mx > low) & (mx < high);
            const float a = ok ? sarea[j] : INFINITY;
            if (a < best) { best = a; idx = j; }
        }
        const bool pos = (best < INFINITY);

        // matched regression target
        const float x0 = sb[4*idx], y0 = sb[4*idx+1], x1 = sb[4*idx+2], y1 = sb[4*idx+3];
        const float tl = x - x0, tt = y - y0, tr = x1 - x, tb = y1 - y;

        // predicted l,t,r,b  (channel-first layout: [B,4,H,W])
        const float* rp = rbase + (size_t)b * 4 * hw + ii;
        const float pl = rp[0], pt = rp[hw], pr = rp[2*hw], pb = rp[3*hw];

        // shared iou terms
        const float w_i = fminf(pl, tl) + fminf(pr, tr);
        const float h_i = fminf(pt, tt) + fminf(pb, tb);
        const float a_i = fmaxf(w_i, 0.0f) * fmaxf(h_i, 0.0f);
        const float a_p = (pl + pr) * (pt + pb);
        const float a_t = (tl + tr) * (tt + tb);   // == box area, always > 0
        const float a_u = a_p + a_t - a_i + 1e-7f;
        const float iou_raw = a_i / a_u;

        // giou loss
        const float w_e = fmaxf(pl, tl) + fmaxf(pr, tr);
        const float h_e = fmaxf(pt, tt) + fmaxf(pb, tb);
        const float a_e = fmaxf(w_e, 0.0f) * fmaxf(h_e, 0.0f) + 1e-7f;
        const float gl = 1.0f - (iou_raw - (a_e - a_u) / a_e);

        regl = pos ? gl : 0.0f;
        posf = pos ? 1.0f : 0.0f;
        const float gt_iou = pos ? fminf(fmaxf(iou_raw, 0.0f), 1.0f) : 0.0f;

        // varifocal loss for this anchor (single class channel)
        const float logit = cbase[(size_t)b * hw + ii];
        const float p = 1.0f / (1.0f + expf(-logit));
        const float log_p  = logsig(logit);
        const float log_np = logsig(-logit);
        if (gt_iou > 0.0f)
            clsl = -gt_iou * (gt_iou * log_p + (1.0f - gt_iou) * log_np);
        else
            clsl = -0.75f * p * p * log_np;
    }

    // block reduction: wave shuffle (width 64) then cross-wave via LDS
    float v0 = clsl, v1 = regl, v2 = posf;
    #pragma unroll
    for (int off = 32; off > 0; off >>= 1) {
        v0 += __shfl_down(v0, off);
        v1 += __shfl_down(v1, off);
        v2 += __shfl_down(v2, off);
    }
    __shared__ float red[3][4];
    const int lane = threadIdx.x & 63;
    const int wv   = threadIdx.x >> 6;
    if (lane == 0) { red[0][wv] = v0; red[1][wv] = v1; red[2][wv] = v2; }
    __syncthreads();
    if (threadIdx.x == 0) {
        atomicAdd(&acc[0], red[0][0] + red[0][1] + red[0][2] + red[0][3]);
        atomicAdd(&acc[1], red[1][0] + red[1][1] + red[1][2] + red[1][3]);
        atomicAdd(&acc[2], red[2][0] + red[2][1] + red[2][2] + red[2][3]);
    }
}

__global__ void fcos_final(const float* __restrict__ acc, float* __restrict__ out, int B) {
    const float cls_sum = acc[0];
    const float reg_sum = acc[1];
    const float navg = fmaxf(1.0f, acc[2] / (float)B);
    out[0] = (cls_sum + reg_sum) / navg;
    out[1] = cls_sum / navg;
    out[2] = reg_sum / navg;
}

extern "C" void kernel_launch(void* const* d_in, const int* in_sizes, int n_in,
                              void* d_out, int out_size, void* d_ws, size_t ws_size,
                              hipStream_t stream) {
    const float* cls0 = (const float*)d_in[0];
    const float* cls1 = (const float*)d_in[1];
    const float* cls2 = (const float*)d_in[2];
    const float* reg0 = (const float*)d_in[3];
    const float* reg1 = (const float*)d_in[4];
    const float* reg2 = (const float*)d_in[5];
    const float* boxes = (const float*)d_in[6];

    const int B = in_sizes[0] / NL0;          // 16
    const int M = in_sizes[6] / (4 * B);      // 64

    float* acc = (float*)d_ws;                // [cls_sum, reg_sum, npos, pad]

    fcos_zero<<<1, 64, 0, stream>>>(acc);
    dim3 grid((NTOT + 255) / 256, B);
    fcos_main<<<grid, 256, 0, stream>>>(cls0, cls1, cls2, reg0, reg1, reg2,
                                        boxes, M, acc);
    fcos_final<<<1, 1, 0, stream>>>(acc, (float*)d_out, B);
}

// Round 2
// 105.177 us; speedup vs baseline: 1.5446x; 1.5446x over previous
//
#include <hip/hip_runtime.h>
#include <math.h>

// Level geometry (fixed by reference: strides 4/8/16, H=W=160/80/40)
#define NL0 25600   // 160*160
#define NL1 6400    // 80*80
#define NL2 1600    // 40*40
#define NTOT 33600  // sum (divisible by 4; level bases divisible by 4)
#define MAXM 64

__device__ __forceinline__ float logsig(float x) {
    // numerically stable log(sigmoid(x))
    return fminf(x, 0.0f) - log1pf(expf(-fabsf(x)));
}

// Each thread handles 4 consecutive anchors (same level, same row).
__global__ __launch_bounds__(256) void fcos_main(
    const float* __restrict__ cls0, const float* __restrict__ cls1,
    const float* __restrict__ cls2, const float* __restrict__ reg0,
    const float* __restrict__ reg1, const float* __restrict__ reg2,
    const float* __restrict__ boxes, int M, float* __restrict__ acc)
{
    const int b = blockIdx.y;
    const int base = (blockIdx.x * 256 + threadIdx.x) * 4;

    __shared__ float4 sbox[MAXM];      // x0,y0,x1,y1
    __shared__ unsigned spk[MAXM];     // (area_bits & ~63) | j  -- argmin key

    if (threadIdx.x < M) {
        const int j = threadIdx.x;
        float4 bx = ((const float4*)boxes)[(size_t)b * M + j];
        sbox[j] = bx;
        const float area = (bx.z - bx.x) * (bx.w - bx.y);
        spk[j] = (__float_as_uint(area) & ~63u) | (unsigned)j;
    }
    __syncthreads();

    float clsl = 0.0f, regl = 0.0f, posf = 0.0f;

    if (base < NTOT) {
        int ii, hw;
        float s, low, high, x0, y;
        const float* cbase;
        const float* rbase;
        if (base < NL0) {
            ii = base; hw = NL0; s = 4.0f; low = -1.0f; high = 64.0f;
            cbase = cls0; rbase = reg0;
            const int h = ii / 160, w = ii - h * 160;
            x0 = ((float)w + 0.5f) * s; y = ((float)h + 0.5f) * s;
        } else if (base < NL0 + NL1) {
            ii = base - NL0; hw = NL1; s = 8.0f; low = 64.0f; high = 128.0f;
            cbase = cls1; rbase = reg1;
            const int h = ii / 80, w = ii - h * 80;
            x0 = ((float)w + 0.5f) * s; y = ((float)h + 0.5f) * s;
        } else {
            ii = base - (NL0 + NL1); hw = NL2; s = 16.0f; low = 128.0f; high = 99999.0f;
            cbase = cls2; rbase = reg2;
            const int h = ii / 40, w = ii - h * 40;
            x0 = ((float)w + 0.5f) * s; y = ((float)h + 0.5f) * s;
        }
        const float xk[4] = { x0, x0 + s, x0 + 2.0f * s, x0 + 3.0f * s };

        unsigned best[4] = { 0xFFFFFFFFu, 0xFFFFFFFFu, 0xFFFFFFFFu, 0xFFFFFFFFu };

        #pragma unroll 4
        for (int j = 0; j < M; ++j) {
            const float4 bx = sbox[j];          // broadcast ds_read_b128
            const unsigned pk = spk[j];
            const float t  = y - bx.y;
            const float bo = bx.w - y;
            const float mtb = fminf(t, bo);
            const float xtb = fmaxf(t, bo);
            const float l0 = x0 - bx.x;
            const float r0 = bx.z - x0;
            #pragma unroll
            for (int k = 0; k < 4; ++k) {
                const float ks = (float)k * s;
                const float l = l0 + ks;
                const float r = r0 - ks;
                const float mn = fminf(fminf(l, r), mtb);
                const float mx = fmaxf(fmaxf(l, r), xtb);
                const bool ok = (mn > 0.0f) & (mx > low) & (mx < high);
                const unsigned cand = ok ? pk : 0xFFFFFFFFu;
                best[k] = min(best[k], cand);
            }
        }

        // vectorized global loads: 4 consecutive anchors per channel
        const float* rp = rbase + (size_t)b * 4 * hw + ii;
        const float4 pl4 = *(const float4*)(rp);
        const float4 pt4 = *(const float4*)(rp + hw);
        const float4 pr4 = *(const float4*)(rp + 2 * hw);
        const float4 pb4 = *(const float4*)(rp + 3 * hw);
        const float4 lg4 = *(const float4*)(cbase + (size_t)b * hw + ii);
        const float* plv = (const float*)&pl4;
        const float* ptv = (const float*)&pt4;
        const float* prv = (const float*)&pr4;
        const float* pbv = (const float*)&pb4;
        const float* lgv = (const float*)&lg4;

        #pragma unroll
        for (int k = 0; k < 4; ++k) {
            const bool pos = (best[k] != 0xFFFFFFFFu);
            const int idx = (int)(best[k] & 63u);
            const float4 tbx = sbox[idx];       // divergent, 1 per anchor, cheap
            const float xc = xk[k];
            const float tl = xc - tbx.x, tt = y - tbx.y;
            const float tr = tbx.z - xc, tb = tbx.w - y;

            const float pl = plv[k], pt = ptv[k], pr = prv[k], pb = pbv[k];

            const float w_i = fminf(pl, tl) + fminf(pr, tr);
            const float h_i = fminf(pt, tt) + fminf(pb, tb);
            const float a_i = fmaxf(w_i, 0.0f) * fmaxf(h_i, 0.0f);
            const float a_p = (pl + pr) * (pt + pb);
            const float a_t = (tl + tr) * (tt + tb);
            const float a_u = a_p + a_t - a_i + 1e-7f;
            const float iou_raw = a_i / a_u;

            const float w_e = fmaxf(pl, tl) + fmaxf(pr, tr);
            const float h_e = fmaxf(pt, tt) + fmaxf(pb, tb);
            const float a_e = fmaxf(w_e, 0.0f) * fmaxf(h_e, 0.0f) + 1e-7f;
            const float gl = 1.0f - (iou_raw - (a_e - a_u) / a_e);

            regl += pos ? gl : 0.0f;
            posf += pos ? 1.0f : 0.0f;
            const float gt_iou = pos ? fminf(fmaxf(iou_raw, 0.0f), 1.0f) : 0.0f;

            const float logit = lgv[k];
            const float p = 1.0f / (1.0f + expf(-logit));
            const float log_p  = logsig(logit);
            const float log_np = logsig(-logit);
            if (gt_iou > 0.0f)
                clsl += -gt_iou * (gt_iou * log_p + (1.0f - gt_iou) * log_np);
            else
                clsl += -0.75f * p * p * log_np;
        }
    }

    // block reduction: wave shuffle (width 64) then cross-wave via LDS
    float v0 = clsl, v1 = regl, v2 = posf;
    #pragma unroll
    for (int off = 32; off > 0; off >>= 1) {
        v0 += __shfl_down(v0, off);
        v1 += __shfl_down(v1, off);
        v2 += __shfl_down(v2, off);
    }
    __shared__ float red[3][4];
    const int lane = threadIdx.x & 63;
    const int wv   = threadIdx.x >> 6;
    if (lane == 0) { red[0][wv] = v0; red[1][wv] = v1; red[2][wv] = v2; }
    __syncthreads();
    if (threadIdx.x == 0) {
        atomicAdd(&acc[0], red[0][0] + red[0][1] + red[0][2] + red[0][3]);
        atomicAdd(&acc[1], red[1][0] + red[1][1] + red[1][2] + red[1][3]);
        atomicAdd(&acc[2], red[2][0] + red[2][1] + red[2][2] + red[2][3]);
    }
}

__global__ void fcos_final(const float* __restrict__ acc, float* __restrict__ out, int B) {
    const float cls_sum = acc[0];
    const float reg_sum = acc[1];
    const float navg = fmaxf(1.0f, acc[2] / (float)B);
    out[0] = (cls_sum + reg_sum) / navg;
    out[1] = cls_sum / navg;
    out[2] = reg_sum / navg;
}

extern "C" void kernel_launch(void* const* d_in, const int* in_sizes, int n_in,
                              void* d_out, int out_size, void* d_ws, size_t ws_size,
                              hipStream_t stream) {
    const float* cls0 = (const float*)d_in[0];
    const float* cls1 = (const float*)d_in[1];
    const float* cls2 = (const float*)d_in[2];
    const float* reg0 = (const float*)d_in[3];
    const float* reg1 = (const float*)d_in[4];
    const float* reg2 = (const float*)d_in[5];
    const float* boxes = (const float*)d_in[6];

    const int B = in_sizes[0] / NL0;          // 16
    const int M = in_sizes[6] / (4 * B);      // 64

    float* acc = (float*)d_ws;                // [cls_sum, reg_sum, npos]

    hipMemsetAsync(acc, 0, 3 * sizeof(float), stream);
    dim3 grid((NTOT / 4 + 255) / 256, B);
    fcos_main<<<grid, 256, 0, stream>>>(cls0, cls1, cls2, reg0, reg1, reg2,
                                        boxes, M, acc);
    fcos_final<<<1, 1, 0, stream>>>(acc, (float*)d_out, B);
}